// Round 1
// baseline (505.848 us; speedup 1.0000x reference)
//
#include <hip/hip_runtime.h>

#define NSIDE 128
#define NPIX (12 * NSIDE * NSIDE)   // 196608
#define BB 8
#define CIN 16
#define COUT 32
#define NROW (NPIX + 1)             // padded rows per batch

typedef _Float16 half8 __attribute__((ext_vector_type(8)));
typedef float floatx16 __attribute__((ext_vector_type(16)));
typedef float float4v __attribute__((ext_vector_type(4)));

// Fused prep:
//  - transpose+cast x (B, CIN, NPIX) f32 -> xt (B, NPIX+1, CIN) f16 (4 pixels/thread, float4 reads)
//  - zero the pad row per batch
//  - build wf A-fragment table (block 0 only)
__global__ __launch_bounds__(256) void prep_xt(const float* __restrict__ x,
                                               _Float16* __restrict__ xt,
                                               const float* __restrict__ w,
                                               _Float16* __restrict__ wf) {
    const int QPB = NPIX / 4;                      // 49152 quads per batch
    int t = blockIdx.x * 256 + threadIdx.x;        // [0, BB*QPB)
    int b = t / QPB;
    int q = t - b * QPB;
    long p0 = (long)q * 4;

    const float* xb = x + (long)b * CIN * NPIX + p0;
    half8 lo[4], hi[4];
#pragma unroll
    for (int c = 0; c < 8; c++) {
        float4v v = __builtin_nontemporal_load((const float4v*)(xb + (long)c * NPIX));
#pragma unroll
        for (int i = 0; i < 4; i++) lo[i][c] = (_Float16)v[i];
    }
#pragma unroll
    for (int c = 0; c < 8; c++) {
        float4v v = __builtin_nontemporal_load((const float4v*)(xb + (long)(c + 8) * NPIX));
#pragma unroll
        for (int i = 0; i < 4; i++) hi[i][c] = (_Float16)v[i];
    }
    half8* dst = (half8*)(xt + ((long)b * NROW + p0) * 16);
#pragma unroll
    for (int i = 0; i < 4; i++) {
        __builtin_nontemporal_store(lo[i], dst + 2 * i);
        __builtin_nontemporal_store(hi[i], dst + 2 * i + 1);
    }

    // pad row (index NPIX) per batch = zeros
    if (t < BB) {
        half8 z = (_Float16)0.f;
        half8* pz = (half8*)(xt + ((long)t * NROW + NPIX) * 16);
        pz[0] = z;
        pz[1] = z;
    }

    // weights (COUT, CIN, 9) f32 -> A-frag layout wf[(k*64+lane)*8 + j] f16
    if (blockIdx.x == 0) {
        for (int e = threadIdx.x; e < 9 * 64 * 8; e += 256) {
            int k    = e >> 9;
            int lane = (e >> 3) & 63;
            int j    = e & 7;
            int o    = lane & 31;
            int c    = ((lane >> 5) << 3) + j;
            wf[e] = (_Float16)w[(o * CIN + c) * 9 + k];
        }
    }
}

// One wave per 32-pixel tile: out[32 o][32 p] = sum over 9 MFMAs (K=16=CIN each).
// XCD-batch affinity: blockIdx.x % 8 == batch == XCD (round-robin dispatch),
// so each XCD's gather working set is one batch's xt (6.3 MB) in its 4 MiB L2.
__global__ __launch_bounds__(256) void conv_main(const _Float16* __restrict__ xt,
                                                 const _Float16* __restrict__ wf,
                                                 const float* __restrict__ bias,
                                                 const int* __restrict__ nb,
                                                 float* __restrict__ out) {
    const int lane  = threadIdx.x & 63;
    const int wv    = threadIdx.x >> 6;
    const int b     = blockIdx.x & 7;               // batch == XCD
    const int pt    = (blockIdx.x >> 3) * 4 + wv;   // [0, NPIX/32)
    const int p     = pt * 32 + (lane & 31);
    const int chalf = (lane >> 5) * 8;

    half8 wfrag[9];
#pragma unroll
    for (int k = 0; k < 9; k++)
        wfrag[k] = *(const half8*)(wf + ((k * 64 + lane) << 3));

    // index stream: no reuse within an XCD -> non-temporal
    const int* nbp = nb + p * 9;
    int idx[9];
#pragma unroll
    for (int k = 0; k < 9; k++) idx[k] = __builtin_nontemporal_load(nbp + k);

    const _Float16* xb = xt + (long)b * NROW * 16 + chalf;
    floatx16 acc;
#pragma unroll
    for (int i = 0; i < 16; i++) acc[i] = 0.f;

#pragma unroll
    for (int k = 0; k < 9; k++) {
        half8 v = *(const half8*)(xb + (long)idx[k] * 16);
        acc = __builtin_amdgcn_mfma_f32_32x32x16_f16(wfrag[k], v, acc, 0, 0, 0);
    }

    // C/D layout: col(pixel)=lane&31, row(o)=(r&3)+8*(r>>2)+4*(lane>>5)
    // output is write-once streaming -> non-temporal stores (don't evict xt from L2/L3)
    float* outb = out + ((long)b * COUT) * NPIX + p;
    const int obase = (lane >> 5) << 2;
#pragma unroll
    for (int r = 0; r < 16; r++) {
        int o = (r & 3) + ((r >> 2) << 3) + obase;
        __builtin_nontemporal_store(acc[r] + bias[o], outb + (long)o * NPIX);
    }
}

extern "C" void kernel_launch(void* const* d_in, const int* in_sizes, int n_in,
                              void* d_out, int out_size, void* d_ws, size_t ws_size,
                              hipStream_t stream) {
    const float* x    = (const float*)d_in[0];
    const float* w    = (const float*)d_in[1];
    const float* bias = (const float*)d_in[2];
    const int*   nb   = (const int*)d_in[3];
    float*       out  = (float*)d_out;

    _Float16* wf = (_Float16*)d_ws;                      // 9216 B
    _Float16* xt = (_Float16*)((char*)d_ws + 16384);     // 50.3 MB

    hipLaunchKernelGGL(prep_xt, dim3(BB * NPIX / 4 / 256), dim3(256), 0, stream,
                       x, xt, w, wf);
    hipLaunchKernelGGL(conv_main, dim3(BB * NPIX / 32 / 4), dim3(256), 0, stream,
                       xt, wf, bias, nb, out);
}

// Round 2
// 418.824 us; speedup vs baseline: 1.2078x; 1.2078x over previous
//
#include <hip/hip_runtime.h>

#define NSIDE 128
#define NPIX (12 * NSIDE * NSIDE)   // 196608
#define BB 8
#define CIN 16
#define COUT 32
#define NROW (NPIX + 1)             // padded rows per batch

typedef _Float16 half8 __attribute__((ext_vector_type(8)));
typedef float floatx16 __attribute__((ext_vector_type(16)));
typedef float float4v __attribute__((ext_vector_type(4)));

// Fused prep:
//  - transpose+cast x (B, CIN, NPIX) f32 -> xt (B, NPIX+1, CIN) f16 (4 pixels/thread, float4 reads)
//  - zero the pad row per batch
//  - build wf A-fragment table (block 0 only)
__global__ __launch_bounds__(256) void prep_xt(const float* __restrict__ x,
                                               _Float16* __restrict__ xt,
                                               const float* __restrict__ w,
                                               _Float16* __restrict__ wf) {
    const int QPB = NPIX / 4;                      // 49152 quads per batch
    int t = blockIdx.x * 256 + threadIdx.x;        // [0, BB*QPB)
    int b = t / QPB;
    int q = t - b * QPB;
    long p0 = (long)q * 4;

    const float* xb = x + (long)b * CIN * NPIX + p0;
    half8 lo[4], hi[4];
#pragma unroll
    for (int c = 0; c < 8; c++) {
        float4v v = *(const float4v*)(xb + (long)c * NPIX);
#pragma unroll
        for (int i = 0; i < 4; i++) lo[i][c] = (_Float16)v[i];
    }
#pragma unroll
    for (int c = 0; c < 8; c++) {
        float4v v = *(const float4v*)(xb + (long)(c + 8) * NPIX);
#pragma unroll
        for (int i = 0; i < 4; i++) hi[i][c] = (_Float16)v[i];
    }
    half8* dst = (half8*)(xt + ((long)b * NROW + p0) * 16);
#pragma unroll
    for (int i = 0; i < 4; i++) {
        dst[2 * i]     = lo[i];
        dst[2 * i + 1] = hi[i];
    }

    // pad row (index NPIX) per batch = zeros
    if (t < BB) {
        half8 z = (_Float16)0.f;
        half8* pz = (half8*)(xt + ((long)t * NROW + NPIX) * 16);
        pz[0] = z;
        pz[1] = z;
    }

    // weights (COUT, CIN, 9) f32 -> A-frag layout wf[(k*64+lane)*8 + j] f16
    if (blockIdx.x == 0) {
        for (int e = threadIdx.x; e < 9 * 64 * 8; e += 256) {
            int k    = e >> 9;
            int lane = (e >> 3) & 63;
            int j    = e & 7;
            int o    = lane & 31;
            int c    = ((lane >> 5) << 3) + j;
            wf[e] = (_Float16)w[(o * CIN + c) * 9 + k];
        }
    }
}

// One wave per TWO 32-pixel tiles: 18 independent gathers in flight, 18 MFMAs
// per 9 wfrag loads. XCD-batch affinity: blockIdx.x % 8 == batch == XCD
// (round-robin dispatch), so each XCD's gather working set is one batch's
// xt (6.3 MB) against its 4 MiB L2.
__global__ __launch_bounds__(256) void conv_main(const _Float16* __restrict__ xt,
                                                 const _Float16* __restrict__ wf,
                                                 const float* __restrict__ bias,
                                                 const int* __restrict__ nb,
                                                 float* __restrict__ out) {
    const int lane  = threadIdx.x & 63;
    const int wv    = threadIdx.x >> 6;
    const int b     = blockIdx.x & 7;               // batch == XCD
    const int seg   = blockIdx.x >> 3;              // [0, NPIX/256)
    const int p0    = seg * 256 + wv * 64 + (lane & 31);
    const int p1    = p0 + 32;
    const int chalf = (lane >> 5) * 8;

    half8 wfrag[9];
#pragma unroll
    for (int k = 0; k < 9; k++)
        wfrag[k] = *(const half8*)(wf + ((k * 64 + lane) << 3));

    // index loads head the dependency chain -> keep them cacheable (L2/L3 hits)
    const int* nbp0 = nb + p0 * 9;
    const int* nbp1 = nb + p1 * 9;
    int idx0[9], idx1[9];
#pragma unroll
    for (int k = 0; k < 9; k++) { idx0[k] = nbp0[k]; idx1[k] = nbp1[k]; }

    const _Float16* xb = xt + (long)b * NROW * 16 + chalf;
    floatx16 acc0, acc1;
#pragma unroll
    for (int i = 0; i < 16; i++) { acc0[i] = 0.f; acc1[i] = 0.f; }

#pragma unroll
    for (int k = 0; k < 9; k++) {
        half8 v0 = *(const half8*)(xb + (long)idx0[k] * 16);
        half8 v1 = *(const half8*)(xb + (long)idx1[k] * 16);
        acc0 = __builtin_amdgcn_mfma_f32_32x32x16_f16(wfrag[k], v0, acc0, 0, 0, 0);
        acc1 = __builtin_amdgcn_mfma_f32_32x32x16_f16(wfrag[k], v1, acc1, 0, 0, 0);
    }

    // C/D layout: col(pixel)=lane&31, row(o)=(r&3)+8*(r>>2)+4*(lane>>5)
    float* outb = out + ((long)b * COUT) * NPIX;
    const int obase = (lane >> 5) << 2;
#pragma unroll
    for (int r = 0; r < 16; r++) {
        int o = (r & 3) + ((r >> 2) << 3) + obase;
        float bo = bias[o];
        outb[(long)o * NPIX + p0] = acc0[r] + bo;
        outb[(long)o * NPIX + p1] = acc1[r] + bo;
    }
}

extern "C" void kernel_launch(void* const* d_in, const int* in_sizes, int n_in,
                              void* d_out, int out_size, void* d_ws, size_t ws_size,
                              hipStream_t stream) {
    const float* x    = (const float*)d_in[0];
    const float* w    = (const float*)d_in[1];
    const float* bias = (const float*)d_in[2];
    const int*   nb   = (const int*)d_in[3];
    float*       out  = (float*)d_out;

    _Float16* wf = (_Float16*)d_ws;                      // 9216 B
    _Float16* xt = (_Float16*)((char*)d_ws + 16384);     // 50.3 MB

    hipLaunchKernelGGL(prep_xt, dim3(BB * NPIX / 4 / 256), dim3(256), 0, stream,
                       x, xt, w, wf);
    hipLaunchKernelGGL(conv_main, dim3(BB * NPIX / 256), dim3(256), 0, stream,
                       xt, wf, bias, nb, out);
}

// Round 3
// 405.169 us; speedup vs baseline: 1.2485x; 1.0337x over previous
//
#include <hip/hip_runtime.h>

#define NSIDE 128
#define NPIX (12 * NSIDE * NSIDE)   // 196608
#define BB 8
#define CIN 16
#define COUT 32
#define NROW (NPIX + 1)             // padded rows per batch

typedef _Float16 half8 __attribute__((ext_vector_type(8)));
typedef float floatx16 __attribute__((ext_vector_type(16)));
typedef float float4v __attribute__((ext_vector_type(4)));

// Fused prep:
//  - transpose+cast x (B, CIN, NPIX) f32 -> xt (B, NPIX+1, CIN) f16 (4 pixels/thread, float4 reads)
//  - zero the pad row per batch
//  - build wf A-fragment table (block 0 only)
// All loads/stores CACHEABLE: xt must enter L2/L3 here so conv's gather hits it.
__global__ __launch_bounds__(256) void prep_xt(const float* __restrict__ x,
                                               _Float16* __restrict__ xt,
                                               const float* __restrict__ w,
                                               _Float16* __restrict__ wf) {
    const int QPB = NPIX / 4;                      // 49152 quads per batch
    int t = blockIdx.x * 256 + threadIdx.x;        // [0, BB*QPB)
    int b = t / QPB;
    int q = t - b * QPB;
    long p0 = (long)q * 4;

    const float* xb = x + (long)b * CIN * NPIX + p0;
    half8 lo[4], hi[4];
#pragma unroll
    for (int c = 0; c < 8; c++) {
        float4v v = *(const float4v*)(xb + (long)c * NPIX);
#pragma unroll
        for (int i = 0; i < 4; i++) lo[i][c] = (_Float16)v[i];
    }
#pragma unroll
    for (int c = 0; c < 8; c++) {
        float4v v = *(const float4v*)(xb + (long)(c + 8) * NPIX);
#pragma unroll
        for (int i = 0; i < 4; i++) hi[i][c] = (_Float16)v[i];
    }
    half8* dst = (half8*)(xt + ((long)b * NROW + p0) * 16);
#pragma unroll
    for (int i = 0; i < 4; i++) {
        dst[2 * i]     = lo[i];
        dst[2 * i + 1] = hi[i];
    }

    // pad row (index NPIX) per batch = zeros
    if (t < BB) {
        half8 z = (_Float16)0.f;
        half8* pz = (half8*)(xt + ((long)t * NROW + NPIX) * 16);
        pz[0] = z;
        pz[1] = z;
    }

    // weights (COUT, CIN, 9) f32 -> A-frag layout wf[(k*64+lane)*8 + j] f16
    if (blockIdx.x == 0) {
        for (int e = threadIdx.x; e < 9 * 64 * 8; e += 256) {
            int k    = e >> 9;
            int lane = (e >> 3) & 63;
            int j    = e & 7;
            int o    = lane & 31;
            int c    = ((lane >> 5) << 3) + j;
            wf[e] = (_Float16)w[(o * CIN + c) * 9 + k];
        }
    }
}

// One wave per TWO 32-pixel tiles: 18 independent gathers in flight, 18 MFMAs
// per 9 wfrag loads. XCD-batch affinity: blockIdx.x % 8 == batch == XCD
// (round-robin dispatch) -> per-XCD gather working set = one batch's xt (6.3 MB).
// Output stores are NON-TEMPORAL (write-once stream, 201 MB/iter) so they do
// not evict xt from L2/L3 -- the gather's L2 misses must be served by L3,
// not HBM. Index (nb) and xt loads stay cacheable (they head the dep chain).
__global__ __launch_bounds__(256) void conv_main(const _Float16* __restrict__ xt,
                                                 const _Float16* __restrict__ wf,
                                                 const float* __restrict__ bias,
                                                 const int* __restrict__ nb,
                                                 float* __restrict__ out) {
    const int lane  = threadIdx.x & 63;
    const int wv    = threadIdx.x >> 6;
    const int b     = blockIdx.x & 7;               // batch == XCD
    const int seg   = blockIdx.x >> 3;              // [0, NPIX/256)
    const int p0    = seg * 256 + wv * 64 + (lane & 31);
    const int p1    = p0 + 32;
    const int chalf = (lane >> 5) * 8;

    half8 wfrag[9];
#pragma unroll
    for (int k = 0; k < 9; k++)
        wfrag[k] = *(const half8*)(wf + ((k * 64 + lane) << 3));

    // index loads head the dependency chain -> keep them cacheable
    const int* nbp0 = nb + p0 * 9;
    const int* nbp1 = nb + p1 * 9;
    int idx0[9], idx1[9];
#pragma unroll
    for (int k = 0; k < 9; k++) { idx0[k] = nbp0[k]; idx1[k] = nbp1[k]; }

    const _Float16* xb = xt + (long)b * NROW * 16 + chalf;
    floatx16 acc0, acc1;
#pragma unroll
    for (int i = 0; i < 16; i++) { acc0[i] = 0.f; acc1[i] = 0.f; }

#pragma unroll
    for (int k = 0; k < 9; k++) {
        half8 v0 = *(const half8*)(xb + (long)idx0[k] * 16);
        half8 v1 = *(const half8*)(xb + (long)idx1[k] * 16);
        acc0 = __builtin_amdgcn_mfma_f32_32x32x16_f16(wfrag[k], v0, acc0, 0, 0, 0);
        acc1 = __builtin_amdgcn_mfma_f32_32x32x16_f16(wfrag[k], v1, acc1, 0, 0, 0);
    }

    // C/D layout: col(pixel)=lane&31, row(o)=(r&3)+8*(r>>2)+4*(lane>>5)
    float* outb = out + ((long)b * COUT) * NPIX;
    const int obase = (lane >> 5) << 2;
#pragma unroll
    for (int r = 0; r < 16; r++) {
        int o = (r & 3) + ((r >> 2) << 3) + obase;
        float bo = bias[o];
        __builtin_nontemporal_store(acc0[r] + bo, outb + (long)o * NPIX + p0);
        __builtin_nontemporal_store(acc1[r] + bo, outb + (long)o * NPIX + p1);
    }
}

extern "C" void kernel_launch(void* const* d_in, const int* in_sizes, int n_in,
                              void* d_out, int out_size, void* d_ws, size_t ws_size,
                              hipStream_t stream) {
    const float* x    = (const float*)d_in[0];
    const float* w    = (const float*)d_in[1];
    const float* bias = (const float*)d_in[2];
    const int*   nb   = (const int*)d_in[3];
    float*       out  = (float*)d_out;

    _Float16* wf = (_Float16*)d_ws;                      // 9216 B
    _Float16* xt = (_Float16*)((char*)d_ws + 16384);     // 50.3 MB

    hipLaunchKernelGGL(prep_xt, dim3(BB * NPIX / 4 / 256), dim3(256), 0, stream,
                       x, xt, w, wf);
    hipLaunchKernelGGL(conv_main, dim3(BB * NPIX / 256), dim3(256), 0, stream,
                       xt, wf, bias, nb, out);
}

// Round 4
// 396.561 us; speedup vs baseline: 1.2756x; 1.0217x over previous
//
#include <hip/hip_runtime.h>

#define NSIDE 128
#define NPIX (12 * NSIDE * NSIDE)   // 196608
#define BB 8
#define CIN 16
#define COUT 32
#define NROW (NPIX + 1)             // padded rows per batch
#define CHUNK 1024                  // pixels per prep block
#define LSTR 1032                   // LDS row stride in f16 (pad 8 = 16B)

typedef _Float16 half4 __attribute__((ext_vector_type(4)));
typedef _Float16 half8 __attribute__((ext_vector_type(8)));
typedef float floatx16 __attribute__((ext_vector_type(16)));
typedef float float4v __attribute__((ext_vector_type(4)));

// LDS-staged transpose+cast: x (B, CIN, NPIX) f32 -> xt (B, NPIX+1, CIN) f16.
// Old version: each thread read 16 streams at stride 768 KiB (channel-interleave
// aliasing -> each wave serialized on one HBM channel). New version: each wave
// reads 4 channels in 1KB-contiguous instructions, stages in LDS, then writes
// the same contiguous 32B rows. All accesses cacheable (xt must land in L2/L3).
__global__ __launch_bounds__(256) void prep_xt(const float* __restrict__ x,
                                               _Float16* __restrict__ xt,
                                               const float* __restrict__ w,
                                               _Float16* __restrict__ wf) {
    __shared__ _Float16 lds[CIN * LSTR];        // 33 KB
    const int b     = blockIdx.x & 7;
    const int chunk = blockIdx.x >> 3;          // [0, NPIX/CHUNK)
    const int wv    = threadIdx.x >> 6;
    const int lane  = threadIdx.x & 63;

    // read phase: wave wv covers channels 4wv..4wv+3, 1KB contiguous per instr
    const float* xb = x + (long)b * CIN * NPIX + (long)chunk * CHUNK;
#pragma unroll
    for (int cc = 0; cc < 4; cc++) {
        const int c = wv * 4 + cc;
        const float* xc = xb + (long)c * NPIX;
#pragma unroll
        for (int j = 0; j < 4; j++) {
            const int px = j * 256 + lane * 4;
            float4v v = *(const float4v*)(xc + px);
            half4 h = { (_Float16)v[0], (_Float16)v[1], (_Float16)v[2], (_Float16)v[3] };
            *(half4*)(lds + c * LSTR + px) = h;
        }
    }
    __syncthreads();

    // write phase: thread t emits rows 4t..4t+3 (128B contiguous per thread)
    const int p0 = threadIdx.x * 4;
    half4 ch[CIN];
#pragma unroll
    for (int c = 0; c < CIN; c++)
        ch[c] = *(const half4*)(lds + c * LSTR + p0);

    _Float16* dst = xt + ((long)b * NROW + (long)chunk * CHUNK + p0) * CIN;
#pragma unroll
    for (int i = 0; i < 4; i++) {
        half8 lo, hi;
#pragma unroll
        for (int c = 0; c < 8; c++) { lo[c] = ch[c][i]; hi[c] = ch[c + 8][i]; }
        *(half8*)(dst + (long)i * CIN)     = lo;
        *(half8*)(dst + (long)i * CIN + 8) = hi;
    }

    if (blockIdx.x == 0) {
        // pad row (index NPIX) per batch = zeros
        if (threadIdx.x < BB) {
            half8 z = (_Float16)0.f;
            half8* pz = (half8*)(xt + ((long)threadIdx.x * NROW + NPIX) * CIN);
            pz[0] = z;
            pz[1] = z;
        }
        // weights (COUT, CIN, 9) f32 -> A-frag layout wf[(k*64+lane)*8 + j] f16
        for (int e = threadIdx.x; e < 9 * 64 * 8; e += 256) {
            int k    = e >> 9;
            int lane2 = (e >> 3) & 63;
            int j    = e & 7;
            int o    = lane2 & 31;
            int c    = ((lane2 >> 5) << 3) + j;
            wf[e] = (_Float16)w[(o * CIN + c) * 9 + k];
        }
    }
}

// One wave per TWO 32-pixel tiles: 18 independent gathers in flight, 18 MFMAs
// per 9 wfrag loads. XCD-batch affinity: blockIdx.x % 8 == batch == XCD
// (round-robin dispatch) -> per-XCD gather working set = one batch's xt (6.3 MB).
// Output stores NON-TEMPORAL (write-once stream). nb/xt loads cacheable.
// UNCHANGED from round 3 (A/B isolation: this round only touches prep).
__global__ __launch_bounds__(256) void conv_main(const _Float16* __restrict__ xt,
                                                 const _Float16* __restrict__ wf,
                                                 const float* __restrict__ bias,
                                                 const int* __restrict__ nb,
                                                 float* __restrict__ out) {
    const int lane  = threadIdx.x & 63;
    const int wv    = threadIdx.x >> 6;
    const int b     = blockIdx.x & 7;               // batch == XCD
    const int seg   = blockIdx.x >> 3;              // [0, NPIX/256)
    const int p0    = seg * 256 + wv * 64 + (lane & 31);
    const int p1    = p0 + 32;
    const int chalf = (lane >> 5) * 8;

    half8 wfrag[9];
#pragma unroll
    for (int k = 0; k < 9; k++)
        wfrag[k] = *(const half8*)(wf + ((k * 64 + lane) << 3));

    const int* nbp0 = nb + p0 * 9;
    const int* nbp1 = nb + p1 * 9;
    int idx0[9], idx1[9];
#pragma unroll
    for (int k = 0; k < 9; k++) { idx0[k] = nbp0[k]; idx1[k] = nbp1[k]; }

    const _Float16* xb = xt + (long)b * NROW * 16 + chalf;
    floatx16 acc0, acc1;
#pragma unroll
    for (int i = 0; i < 16; i++) { acc0[i] = 0.f; acc1[i] = 0.f; }

#pragma unroll
    for (int k = 0; k < 9; k++) {
        half8 v0 = *(const half8*)(xb + (long)idx0[k] * 16);
        half8 v1 = *(const half8*)(xb + (long)idx1[k] * 16);
        acc0 = __builtin_amdgcn_mfma_f32_32x32x16_f16(wfrag[k], v0, acc0, 0, 0, 0);
        acc1 = __builtin_amdgcn_mfma_f32_32x32x16_f16(wfrag[k], v1, acc1, 0, 0, 0);
    }

    float* outb = out + ((long)b * COUT) * NPIX;
    const int obase = (lane >> 5) << 2;
#pragma unroll
    for (int r = 0; r < 16; r++) {
        int o = (r & 3) + ((r >> 2) << 3) + obase;
        float bo = bias[o];
        __builtin_nontemporal_store(acc0[r] + bo, outb + (long)o * NPIX + p0);
        __builtin_nontemporal_store(acc1[r] + bo, outb + (long)o * NPIX + p1);
    }
}

extern "C" void kernel_launch(void* const* d_in, const int* in_sizes, int n_in,
                              void* d_out, int out_size, void* d_ws, size_t ws_size,
                              hipStream_t stream) {
    const float* x    = (const float*)d_in[0];
    const float* w    = (const float*)d_in[1];
    const float* bias = (const float*)d_in[2];
    const int*   nb   = (const int*)d_in[3];
    float*       out  = (float*)d_out;

    _Float16* wf = (_Float16*)d_ws;                      // 9216 B
    _Float16* xt = (_Float16*)((char*)d_ws + 16384);     // 50.3 MB

    hipLaunchKernelGGL(prep_xt, dim3(BB * NPIX / CHUNK), dim3(256), 0, stream,
                       x, xt, w, wf);
    hipLaunchKernelGGL(conv_main, dim3(BB * NPIX / 256), dim3(256), 0, stream,
                       xt, wf, bias, nb, out);
}

// Round 5
// 394.458 us; speedup vs baseline: 1.2824x; 1.0053x over previous
//
#include <hip/hip_runtime.h>

#define NSIDE 128
#define NPIX (12 * NSIDE * NSIDE)   // 196608
#define BB 8
#define CIN 16
#define COUT 32
#define NROW (NPIX + 1)             // padded rows per batch
#define CHUNK 256                   // pixels per prep block
#define LSTR 264                    // LDS row stride in f16 (256 + 8 pad)

typedef _Float16 half4 __attribute__((ext_vector_type(4)));
typedef _Float16 half8 __attribute__((ext_vector_type(8)));
typedef float floatx16 __attribute__((ext_vector_type(16)));
typedef float float4v __attribute__((ext_vector_type(4)));

// LDS-staged transpose+cast: x (B, CIN, NPIX) f32 -> xt (B, NPIX+1, CIN) f16.
// One row per thread. Read phase: wave wv covers channels 4wv..4wv+3, one
// float4 per lane = 1KB contiguous per instruction. Write phase: thread t
// emits row t (32B) as two 16B stores with lanes at 32B stride = 2KB
// contiguous per instruction (previous version had 128B/lane stride ->
// one 64B line per lane per store). All accesses cacheable.
__global__ __launch_bounds__(256) void prep_xt(const float* __restrict__ x,
                                               _Float16* __restrict__ xt,
                                               const float* __restrict__ w,
                                               _Float16* __restrict__ wf) {
    __shared__ _Float16 lds[CIN * LSTR];        // 8448 B
    const int b     = blockIdx.x & 7;           // batch == XCD (matches conv)
    const int chunk = blockIdx.x >> 3;          // [0, NPIX/CHUNK)
    const int wv    = threadIdx.x >> 6;
    const int lane  = threadIdx.x & 63;

    const float* xb = x + (long)b * CIN * NPIX + (long)chunk * CHUNK;
#pragma unroll
    for (int cc = 0; cc < 4; cc++) {
        const int c = wv * 4 + cc;
        float4v v = *(const float4v*)(xb + (long)c * NPIX + lane * 4);
        half4 h = { (_Float16)v[0], (_Float16)v[1], (_Float16)v[2], (_Float16)v[3] };
        *(half4*)(lds + c * LSTR + lane * 4) = h;
    }
    __syncthreads();

    const int t = threadIdx.x;                  // row within chunk
    half8 lo, hi;
#pragma unroll
    for (int c = 0; c < 8; c++) lo[c] = lds[c * LSTR + t];
#pragma unroll
    for (int c = 0; c < 8; c++) hi[c] = lds[(c + 8) * LSTR + t];

    _Float16* dst = xt + ((long)b * NROW + (long)chunk * CHUNK + t) * CIN;
    *(half8*)(dst)     = lo;
    *(half8*)(dst + 8) = hi;

    if (blockIdx.x == 0) {
        // pad row (index NPIX) per batch = zeros
        if (threadIdx.x < BB) {
            half8 z = (_Float16)0.f;
            half8* pz = (half8*)(xt + ((long)threadIdx.x * NROW + NPIX) * CIN);
            pz[0] = z;
            pz[1] = z;
        }
        // weights (COUT, CIN, 9) f32 -> A-frag layout wf[(k*64+lane)*8 + j] f16
        for (int e = threadIdx.x; e < 9 * 64 * 8; e += 256) {
            int k     = e >> 9;
            int lane2 = (e >> 3) & 63;
            int j     = e & 7;
            int o     = lane2 & 31;
            int c     = ((lane2 >> 5) << 3) + j;
            wf[e] = (_Float16)w[(o * CIN + c) * 9 + k];
        }
    }
}

// One wave per TWO 32-pixel tiles: 18 independent gathers in flight, 18 MFMAs
// per 9 wfrag loads. XCD-batch affinity: blockIdx.x % 8 == batch == XCD
// (round-robin dispatch) -> per-XCD gather working set = one batch's xt (6.3 MB).
// Output stores NON-TEMPORAL (write-once stream). nb/xt loads cacheable.
// UNCHANGED from rounds 3-4: counters show it at ~95% of its structural
// floor (590 MB min traffic at the ~4.3 TB/s random-mix service ceiling).
__global__ __launch_bounds__(256) void conv_main(const _Float16* __restrict__ xt,
                                                 const _Float16* __restrict__ wf,
                                                 const float* __restrict__ bias,
                                                 const int* __restrict__ nb,
                                                 float* __restrict__ out) {
    const int lane  = threadIdx.x & 63;
    const int wv    = threadIdx.x >> 6;
    const int b     = blockIdx.x & 7;               // batch == XCD
    const int seg   = blockIdx.x >> 3;              // [0, NPIX/256)
    const int p0    = seg * 256 + wv * 64 + (lane & 31);
    const int p1    = p0 + 32;
    const int chalf = (lane >> 5) * 8;

    half8 wfrag[9];
#pragma unroll
    for (int k = 0; k < 9; k++)
        wfrag[k] = *(const half8*)(wf + ((k * 64 + lane) << 3));

    const int* nbp0 = nb + p0 * 9;
    const int* nbp1 = nb + p1 * 9;
    int idx0[9], idx1[9];
#pragma unroll
    for (int k = 0; k < 9; k++) { idx0[k] = nbp0[k]; idx1[k] = nbp1[k]; }

    const _Float16* xb = xt + (long)b * NROW * 16 + chalf;
    floatx16 acc0, acc1;
#pragma unroll
    for (int i = 0; i < 16; i++) { acc0[i] = 0.f; acc1[i] = 0.f; }

#pragma unroll
    for (int k = 0; k < 9; k++) {
        half8 v0 = *(const half8*)(xb + (long)idx0[k] * 16);
        half8 v1 = *(const half8*)(xb + (long)idx1[k] * 16);
        acc0 = __builtin_amdgcn_mfma_f32_32x32x16_f16(wfrag[k], v0, acc0, 0, 0, 0);
        acc1 = __builtin_amdgcn_mfma_f32_32x32x16_f16(wfrag[k], v1, acc1, 0, 0, 0);
    }

    float* outb = out + ((long)b * COUT) * NPIX;
    const int obase = (lane >> 5) << 2;
#pragma unroll
    for (int r = 0; r < 16; r++) {
        int o = (r & 3) + ((r >> 2) << 3) + obase;
        float bo = bias[o];
        __builtin_nontemporal_store(acc0[r] + bo, outb + (long)o * NPIX + p0);
        __builtin_nontemporal_store(acc1[r] + bo, outb + (long)o * NPIX + p1);
    }
}

extern "C" void kernel_launch(void* const* d_in, const int* in_sizes, int n_in,
                              void* d_out, int out_size, void* d_ws, size_t ws_size,
                              hipStream_t stream) {
    const float* x    = (const float*)d_in[0];
    const float* w    = (const float*)d_in[1];
    const float* bias = (const float*)d_in[2];
    const int*   nb   = (const int*)d_in[3];
    float*       out  = (float*)d_out;

    _Float16* wf = (_Float16*)d_ws;                      // 9216 B
    _Float16* xt = (_Float16*)((char*)d_ws + 16384);     // 50.3 MB

    hipLaunchKernelGGL(prep_xt, dim3(BB * NPIX / CHUNK), dim3(256), 0, stream,
                       x, xt, w, wf);
    hipLaunchKernelGGL(conv_main, dim3(BB * NPIX / 256), dim3(256), 0, stream,
                       xt, wf, bias, nb, out);
}